// Round 6
// baseline (400.002 us; speedup 1.0000x reference)
//
#include <hip/hip_runtime.h>
#include <hip/hip_bf16.h>

#define CAP 32   // padded adjacency slots per node per sign (Poisson λ≈6.25)

// ---------------------------------------------------------------------------
// Build per-dst adjacency lists (padded, CAP slots) + per-sign degree counts.
// ---------------------------------------------------------------------------
__global__ __launch_bounds__(256) void pg_build(
    const int* __restrict__ ei,
    int* __restrict__ plist, int* __restrict__ nlist,
    int* __restrict__ pcur, int* __restrict__ ncur, int E)
{
    int e = blockIdx.x * 256 + threadIdx.x;
    if (e >= E) return;
    int s  = ei[3 * e + 0];
    int d  = ei[3 * e + 1];
    int sg = ei[3 * e + 2];
    if (sg > 0) {
        int slot = atomicAdd(pcur + d, 1);
        if (slot < CAP) plist[d * CAP + slot] = s;
    } else {
        int slot = atomicAdd(ncur + d, 1);
        if (slot < CAP) nlist[d * CAP + slot] = s;
    }
}

// ---------------------------------------------------------------------------
// Gather: per node, pos-mean and neg-mean of src rows -> packed bf16 row
//   agg[i] = [ pmean(64) | nmean(64) ]
// No LDS; high occupancy for latency hiding. 4 nodes per wave batch,
// 32 row-loads in flight per iteration.
// ---------------------------------------------------------------------------
__global__ __launch_bounds__(256, 6) void pg_gather(
    const float* __restrict__ src,
    const int* __restrict__ plist, const int* __restrict__ nlist,
    const int* __restrict__ pcur, const int* __restrict__ ncur,
    __hip_bfloat16* __restrict__ agg, int N)
{
    int tid = threadIdx.x;
    int w = tid >> 6, lane = tid & 63;

    #pragma unroll 1
    for (int g = 0; g < 4; ++g) {
        int i0 = blockIdx.x * 64 + w * 16 + g * 4;
        int pd[4], nd[4], pde[4], nde[4], pl[4], nl[4];
        #pragma unroll
        for (int n = 0; n < 4; ++n) {
            int i = min(i0 + n, N - 1);
            pd[n] = __builtin_amdgcn_readfirstlane(pcur[i]);
            nd[n] = __builtin_amdgcn_readfirstlane(ncur[i]);
            pde[n] = min(pd[n], CAP);
            nde[n] = min(nd[n], CAP);
            const int* plrow = plist + (size_t)i * CAP;
            const int* nlrow = nlist + (size_t)i * CAP;
            pl[n] = plrow[lane & 31];
            nl[n] = nlrow[lane & 31];
        }
        int maxd = 0;
        #pragma unroll
        for (int n = 0; n < 4; ++n) maxd = max(maxd, max(pde[n], nde[n]));

        float ps[4] = {0.f, 0.f, 0.f, 0.f}, ns[4] = {0.f, 0.f, 0.f, 0.f};
        #pragma unroll 1
        for (int e = 0; e < maxd; e += 4) {
            float pv[4][4], nv[4][4];
            #pragma unroll
            for (int n = 0; n < 4; ++n) {
                #pragma unroll
                for (int k = 0; k < 4; ++k) {
                    int idx = e + k;
                    int psl = (idx < pde[n]) ? idx : 0;
                    int nsl = (idx < nde[n]) ? idx : 0;
                    unsigned sp = (unsigned)__builtin_amdgcn_readlane(pl[n], psl);
                    unsigned sn = (unsigned)__builtin_amdgcn_readlane(nl[n], nsl);
                    sp = sp < (unsigned)N ? sp : 0u;
                    sn = sn < (unsigned)N ? sn : 0u;
                    const float* prow = src + ((size_t)sp << 6);
                    const float* nrow = src + ((size_t)sn << 6);
                    pv[n][k] = prow[lane];
                    nv[n][k] = nrow[lane];
                }
            }
            #pragma unroll
            for (int n = 0; n < 4; ++n) {
                #pragma unroll
                for (int k = 0; k < 4; ++k) {
                    int idx = e + k;
                    float wp  = (idx < pde[n]) ? 1.f : 0.f;
                    float wn_ = (idx < nde[n]) ? 1.f : 0.f;
                    ps[n] = fmaf(wp,  pv[n][k], ps[n]);
                    ns[n] = fmaf(wn_, nv[n][k], ns[n]);
                }
            }
        }
        #pragma unroll
        for (int n = 0; n < 4; ++n) {
            int i = i0 + n;
            if (i < N) {
                __hip_bfloat16* arow = agg + ((size_t)i << 7);
                arow[lane]      = __float2bfloat16(ps[n] / fmaxf((float)pd[n], 1.f));
                arow[64 + lane] = __float2bfloat16(ns[n] / fmaxf((float)nd[n], 1.f));
            }
        }
    }
}

// ---------------------------------------------------------------------------
// GEMM1: z1 = tanh([ap,x]@Wp1 / [an,x]@Wn1), inputs streamed sequentially.
// ---------------------------------------------------------------------------
__global__ __launch_bounds__(256, 3) void pg_gemm1(
    const float* __restrict__ x, const __hip_bfloat16* __restrict__ agg,
    const float* __restrict__ Wp, const float* __restrict__ bp,
    const float* __restrict__ Wn, const float* __restrict__ bn,
    float* __restrict__ z1, int N)
{
    __shared__ __align__(16) float sWp[128 * 32];
    __shared__ __align__(16) float sWn[128 * 32];
    __shared__ __align__(16) float sIn[4][4][192];   // [wave][node][ pv(64) | nv(64) | xv(64) ]

    int tid = threadIdx.x;
    {
        const float4* a = (const float4*)Wp; float4* b = (float4*)sWp;
        const float4* c = (const float4*)Wn; float4* d4 = (float4*)sWn;
        for (int idx = tid; idx < 128 * 32 / 4; idx += 256) { b[idx] = a[idx]; d4[idx] = c[idx]; }
    }
    int w = tid >> 6, lane = tid & 63, j = lane & 31;
    int half = lane >> 5;
    float bv = half ? bn[j] : bp[j];
    __syncthreads();

    const float* W = half ? sWn : sWp;
    int hoff = half * 64;

    #pragma unroll 1
    for (int g = 0; g < 4; ++g) {
        int i0 = blockIdx.x * 64 + w * 16 + g * 4;
        #pragma unroll
        for (int n = 0; n < 4; ++n) {
            int i = min(i0 + n, N - 1);
            const __hip_bfloat16* arow = agg + ((size_t)i << 7);
            const float* xrow = x + ((size_t)i << 6);
            sIn[w][n][lane]       = __bfloat162float(arow[lane]);
            sIn[w][n][64 + lane]  = __bfloat162float(arow[64 + lane]);
            sIn[w][n][128 + lane] = xrow[lane];
        }
        float acc[4][4];
        #pragma unroll
        for (int n = 0; n < 4; ++n)
            #pragma unroll
            for (int r = 0; r < 4; ++r) acc[n][r] = 0.f;
        // agg part: W rows 0..63
        #pragma unroll 2
        for (int k = 0; k < 64; k += 4) {
            float w0 = W[(k + 0) * 32 + j], w1 = W[(k + 1) * 32 + j];
            float w2 = W[(k + 2) * 32 + j], w3 = W[(k + 3) * 32 + j];
            #pragma unroll
            for (int n = 0; n < 4; ++n) {
                float4 iv = *(const float4*)(&sIn[w][n][hoff + k]);
                acc[n][0] = fmaf(iv.x, w0, acc[n][0]);
                acc[n][1] = fmaf(iv.y, w1, acc[n][1]);
                acc[n][2] = fmaf(iv.z, w2, acc[n][2]);
                acc[n][3] = fmaf(iv.w, w3, acc[n][3]);
            }
        }
        // x part: W rows 64..127
        #pragma unroll 2
        for (int k = 0; k < 64; k += 4) {
            float w0 = W[(64 + k + 0) * 32 + j], w1 = W[(64 + k + 1) * 32 + j];
            float w2 = W[(64 + k + 2) * 32 + j], w3 = W[(64 + k + 3) * 32 + j];
            #pragma unroll
            for (int n = 0; n < 4; ++n) {
                float4 iv = *(const float4*)(&sIn[w][n][128 + k]);
                acc[n][0] = fmaf(iv.x, w0, acc[n][0]);
                acc[n][1] = fmaf(iv.y, w1, acc[n][1]);
                acc[n][2] = fmaf(iv.z, w2, acc[n][2]);
                acc[n][3] = fmaf(iv.w, w3, acc[n][3]);
            }
        }
        #pragma unroll
        for (int n = 0; n < 4; ++n) {
            int i = i0 + n;
            if (i < N) {
                float v = bv + ((acc[n][0] + acc[n][1]) + (acc[n][2] + acc[n][3]));
                float* zrow = z1 + ((size_t)i << 6);
                zrow[lane] = tanhf(v);
            }
        }
    }
}

// ---------------------------------------------------------------------------
// GEMM2: z2 = tanh([agg-swizzled, z1]@Wp2/Wn2), z1/z2 share storage (zio).
// ---------------------------------------------------------------------------
__global__ __launch_bounds__(256, 4) void pg_gemm2(
    float* zio, const __hip_bfloat16* __restrict__ agg,
    const float* __restrict__ Wp2, const float* __restrict__ bp2,
    const float* __restrict__ Wn2, const float* __restrict__ bn2,
    int N)
{
    __shared__ __align__(16) float sWp2[96 * 32];
    __shared__ __align__(16) float sWn2[96 * 32];
    __shared__ __align__(16) float sIn[4][4][2][96];

    int tid = threadIdx.x;
    {
        const float4* a = (const float4*)Wp2; float4* b = (float4*)sWp2;
        const float4* c = (const float4*)Wn2; float4* d4 = (float4*)sWn2;
        for (int idx = tid; idx < 96 * 32 / 4; idx += 256) { b[idx] = a[idx]; d4[idx] = c[idx]; }
    }
    int w = tid >> 6, lane = tid & 63, j = lane & 31;
    int half = lane >> 5;
    float bv = half ? bn2[j] : bp2[j];
    __syncthreads();

    const float* W = half ? sWn2 : sWp2;

    #pragma unroll 1
    for (int g = 0; g < 4; ++g) {
        int i0 = blockIdx.x * 64 + w * 16 + g * 4;
        #pragma unroll
        for (int n = 0; n < 4; ++n) {
            int i = min(i0 + n, N - 1);
            const __hip_bfloat16* arow = agg + ((size_t)i << 7);
            float pa = __bfloat162float(arow[lane]);        // pos-mean, col lane
            float na = __bfloat162float(arow[64 + lane]);   // neg-mean, col lane
            float zv = zio[((size_t)i << 6) + lane];        // z1, col lane
            // hp in = [agg_pos(xp), agg_neg(xn), xp]; hn in = [agg_pos(xn), agg_neg(xp), xn]
            if (half == 0) {
                sIn[w][n][0][j]      = pa;    // agg_pos(xp)
                sIn[w][n][1][32 + j] = na;    // agg_neg(xp)
                sIn[w][n][0][64 + j] = zv;    // xp
            } else {
                sIn[w][n][1][j]      = pa;    // agg_pos(xn)
                sIn[w][n][0][32 + j] = na;    // agg_neg(xn)
                sIn[w][n][1][64 + j] = zv;    // xn
            }
        }
        float acc[4][4];
        #pragma unroll
        for (int n = 0; n < 4; ++n)
            #pragma unroll
            for (int r = 0; r < 4; ++r) acc[n][r] = 0.f;
        #pragma unroll 2
        for (int k = 0; k < 96; k += 4) {
            float w0 = W[(k + 0) * 32 + j], w1 = W[(k + 1) * 32 + j];
            float w2 = W[(k + 2) * 32 + j], w3 = W[(k + 3) * 32 + j];
            #pragma unroll
            for (int n = 0; n < 4; ++n) {
                float4 iv = *(const float4*)(&sIn[w][n][half][k]);
                acc[n][0] = fmaf(iv.x, w0, acc[n][0]);
                acc[n][1] = fmaf(iv.y, w1, acc[n][1]);
                acc[n][2] = fmaf(iv.z, w2, acc[n][2]);
                acc[n][3] = fmaf(iv.w, w3, acc[n][3]);
            }
        }
        #pragma unroll
        for (int n = 0; n < 4; ++n) {
            int i = i0 + n;
            if (i < N) {
                float v = bv + ((acc[n][0] + acc[n][1]) + (acc[n][2] + acc[n][3]));
                float* orow = zio + ((size_t)i << 6);
                orow[lane] = tanhf(v);   // z2 overwrites z1 row-locally
            }
        }
    }
}

// ---------------------------------------------------------------------------
// MLP head (row-local): z = tanh(z2@Ww+bw) (in place), BN/ReLU MLP -> prob.
// ---------------------------------------------------------------------------
__global__ __launch_bounds__(256, 3) void pg_mlp(
    float* out,
    const float* __restrict__ Ww,  const float* __restrict__ bw,
    const float* __restrict__ Wm1, const float* __restrict__ bm1,
    const float* __restrict__ g1,  const float* __restrict__ be1,
    const float* __restrict__ rm1, const float* __restrict__ rv1,
    const float* __restrict__ Wm2, const float* __restrict__ bm2,
    const float* __restrict__ g2,  const float* __restrict__ be2,
    const float* __restrict__ rm2, const float* __restrict__ rv2,
    const float* __restrict__ Wm3, const float* __restrict__ bm3,
    int N)
{
    __shared__ __align__(16) float sWw[64 * 64];
    __shared__ __align__(16) float sWm1[64 * 64];
    __shared__ __align__(16) float sWm2[64 * 64];
    __shared__ __align__(16) float sZ[4][4][64];

    int tid = threadIdx.x;
    {
        const float4* a = (const float4*)Ww;  float4* sa = (float4*)sWw;
        const float4* b = (const float4*)Wm1; float4* sb = (float4*)sWm1;
        const float4* c = (const float4*)Wm2; float4* sc = (float4*)sWm2;
        for (int idx = tid; idx < 64 * 64 / 4; idx += 256) { sa[idx] = a[idx]; sb[idx] = b[idx]; sc[idx] = c[idx]; }
    }
    int w = tid >> 6, lane = tid & 63;
    float bwv  = bw[lane];
    float sc1  = g1[lane] * rsqrtf(rv1[lane] + 1e-5f);
    float off1 = (bm1[lane] - rm1[lane]) * sc1 + be1[lane];
    float sc2  = g2[lane] * rsqrtf(rv2[lane] + 1e-5f);
    float off2 = (bm2[lane] - rm2[lane]) * sc2 + be2[lane];
    float wm3  = Wm3[lane];
    float b3   = bm3[0];
    __syncthreads();

    #pragma unroll 1
    for (int g = 0; g < 4; ++g) {
        int i0 = blockIdx.x * 64 + w * 16 + g * 4;
        float vreg[4];
        #pragma unroll
        for (int n = 0; n < 4; ++n) {
            int i = min(i0 + n, N - 1);
            const float* orow = out + ((size_t)i << 6);
            vreg[n] = orow[lane];                                   // z2
            sZ[w][n][lane] = vreg[n];
        }
        float acc[4][4];
        // ---- Ww GEMV -> z ----
        #pragma unroll
        for (int n = 0; n < 4; ++n)
            #pragma unroll
            for (int r = 0; r < 4; ++r) acc[n][r] = 0.f;
        #pragma unroll 2
        for (int k = 0; k < 64; k += 4) {
            float w0 = sWw[(k + 0) * 64 + lane], w1 = sWw[(k + 1) * 64 + lane];
            float w2 = sWw[(k + 2) * 64 + lane], w3 = sWw[(k + 3) * 64 + lane];
            #pragma unroll
            for (int n = 0; n < 4; ++n) {
                float4 iv = *(const float4*)(&sZ[w][n][k]);
                acc[n][0] = fmaf(iv.x, w0, acc[n][0]);
                acc[n][1] = fmaf(iv.y, w1, acc[n][1]);
                acc[n][2] = fmaf(iv.z, w2, acc[n][2]);
                acc[n][3] = fmaf(iv.w, w3, acc[n][3]);
            }
        }
        #pragma unroll
        for (int n = 0; n < 4; ++n) {
            int i = i0 + n;
            vreg[n] = tanhf(bwv + ((acc[n][0] + acc[n][1]) + (acc[n][2] + acc[n][3])));
            if (i < N) {
                float* orow = out + ((size_t)i << 6);
                orow[lane] = vreg[n];                               // final z
            }
        }
        #pragma unroll
        for (int n = 0; n < 4; ++n) sZ[w][n][lane] = vreg[n];
        // ---- Wm1 -> BN -> ReLU ----
        #pragma unroll
        for (int n = 0; n < 4; ++n)
            #pragma unroll
            for (int r = 0; r < 4; ++r) acc[n][r] = 0.f;
        #pragma unroll 2
        for (int k = 0; k < 64; k += 4) {
            float w0 = sWm1[(k + 0) * 64 + lane], w1 = sWm1[(k + 1) * 64 + lane];
            float w2 = sWm1[(k + 2) * 64 + lane], w3 = sWm1[(k + 3) * 64 + lane];
            #pragma unroll
            for (int n = 0; n < 4; ++n) {
                float4 iv = *(const float4*)(&sZ[w][n][k]);
                acc[n][0] = fmaf(iv.x, w0, acc[n][0]);
                acc[n][1] = fmaf(iv.y, w1, acc[n][1]);
                acc[n][2] = fmaf(iv.z, w2, acc[n][2]);
                acc[n][3] = fmaf(iv.w, w3, acc[n][3]);
            }
        }
        #pragma unroll
        for (int n = 0; n < 4; ++n) {
            float a = (acc[n][0] + acc[n][1]) + (acc[n][2] + acc[n][3]);
            sZ[w][n][lane] = fmaxf(a * sc1 + off1, 0.f);
        }
        // ---- Wm2 -> BN -> ReLU -> head ----
        #pragma unroll
        for (int n = 0; n < 4; ++n)
            #pragma unroll
            for (int r = 0; r < 4; ++r) acc[n][r] = 0.f;
        #pragma unroll 2
        for (int k = 0; k < 64; k += 4) {
            float w0 = sWm2[(k + 0) * 64 + lane], w1 = sWm2[(k + 1) * 64 + lane];
            float w2 = sWm2[(k + 2) * 64 + lane], w3 = sWm2[(k + 3) * 64 + lane];
            #pragma unroll
            for (int n = 0; n < 4; ++n) {
                float4 iv = *(const float4*)(&sZ[w][n][k]);
                acc[n][0] = fmaf(iv.x, w0, acc[n][0]);
                acc[n][1] = fmaf(iv.y, w1, acc[n][1]);
                acc[n][2] = fmaf(iv.z, w2, acc[n][2]);
                acc[n][3] = fmaf(iv.w, w3, acc[n][3]);
            }
        }
        #pragma unroll
        for (int n = 0; n < 4; ++n) {
            int i = i0 + n;
            float a = (acc[n][0] + acc[n][1]) + (acc[n][2] + acc[n][3]);
            float h2 = fmaxf(a * sc2 + off2, 0.f);
            float t = h2 * wm3;
            #pragma unroll
            for (int off = 32; off > 0; off >>= 1) t += __shfl_down(t, off, 64);
            if (lane == 0 && i < N) {
                out[(size_t)N * 64 + i] = 1.0f / (1.0f + expf(-(t + b3)));
            }
        }
    }
}

extern "C" void kernel_launch(void* const* d_in, const int* in_sizes, int n_in,
                              void* d_out, int out_size, void* d_ws, size_t ws_size,
                              hipStream_t stream) {
    const float* x   = (const float*)d_in[0];
    const int*   ei  = (const int*)  d_in[1];
    const float* Wp1 = (const float*)d_in[2];
    const float* bp1 = (const float*)d_in[3];
    const float* Wn1 = (const float*)d_in[4];
    const float* bn1 = (const float*)d_in[5];
    const float* Wp2 = (const float*)d_in[6];
    const float* bp2 = (const float*)d_in[7];
    const float* Wn2 = (const float*)d_in[8];
    const float* bn2 = (const float*)d_in[9];
    const float* Ww  = (const float*)d_in[10];
    const float* bw  = (const float*)d_in[11];
    const float* Wm1 = (const float*)d_in[12];
    const float* bm1 = (const float*)d_in[13];
    const float* g1  = (const float*)d_in[14];
    const float* be1 = (const float*)d_in[15];
    const float* rm1 = (const float*)d_in[16];
    const float* rv1 = (const float*)d_in[17];
    const float* Wm2 = (const float*)d_in[18];
    const float* bm2 = (const float*)d_in[19];
    const float* g2  = (const float*)d_in[20];
    const float* be2 = (const float*)d_in[21];
    const float* rm2 = (const float*)d_in[22];
    const float* rv2 = (const float*)d_in[23];
    const float* Wm3 = (const float*)d_in[24];
    const float* bm3 = (const float*)d_in[25];
    float* out = (float*)d_out;

    int N = in_sizes[0] / 64;
    int E = in_sizes[1] / 3;

    // ws layout (52.0 MB for N=100K): plist | nlist | pcur | ncur | agg(bf16 N x 128)
    int* plist = (int*)d_ws;
    int* nlist = plist + (size_t)N * CAP;
    int* pcur  = nlist + (size_t)N * CAP;
    int* ncur  = pcur + N;
    __hip_bfloat16* agg = (__hip_bfloat16*)(ncur + N);
    float* z1 = out;   // z1/z2 staged in d_out's z region (row-local rewrites)

    hipMemsetAsync(pcur, 0, 2 * (size_t)N * sizeof(int), stream);

    pg_build<<<(E + 255) / 256, 256, 0, stream>>>(ei, plist, nlist, pcur, ncur, E);

    int nb = (N + 63) / 64;
    pg_gather<<<nb, 256, 0, stream>>>(x, plist, nlist, pcur, ncur, agg, N);
    pg_gemm1<<<nb, 256, 0, stream>>>(x, agg, Wp1, bp1, Wn1, bn1, z1, N);
    pg_gather<<<nb, 256, 0, stream>>>(z1, plist, nlist, pcur, ncur, agg, N);
    pg_gemm2<<<nb, 256, 0, stream>>>(z1, agg, Wp2, bp2, Wn2, bn2, N);
    pg_mlp<<<nb, 256, 0, stream>>>(out, Ww, bw,
                                   Wm1, bm1, g1, be1, rm1, rv1,
                                   Wm2, bm2, g2, be2, rm2, rv2,
                                   Wm3, bm3, N);
}

// Round 7
// 274.378 us; speedup vs baseline: 1.4579x; 1.4579x over previous
//
#include <hip/hip_runtime.h>
#include <hip/hip_bf16.h>

#define CAP 32   // padded adjacency slots per node per sign (Poisson λ≈6.25)

typedef __attribute__((ext_vector_type(8))) short bf16x8;
typedef __attribute__((ext_vector_type(4))) float f32x4;

#define MFMA(a, b, c) __builtin_amdgcn_mfma_f32_16x16x32_bf16(a, b, c, 0, 0, 0)

__device__ __forceinline__ unsigned short bf16rn(float f) {
    unsigned u = __builtin_bit_cast(unsigned, f);
    u += 0x7fffu + ((u >> 16) & 1u);
    return (unsigned short)(u >> 16);
}

__device__ __forceinline__ bf16x8 packbf8(const float* p) {
    bf16x8 r;
    #pragma unroll
    for (int j = 0; j < 8; ++j) r[j] = (short)bf16rn(p[j]);
    return r;
}

// B-frag from row-major f32 W[K][NN]: elem j = W[kt*32 + q*8 + j][ct*16 + c]
__device__ __forceinline__ bf16x8 wfrag(const float* __restrict__ W, int NN,
                                        int kt, int ct, int q, int c) {
    const float* base = W + (kt * 32 + q * 8) * NN + ct * 16 + c;
    float t[8];
    #pragma unroll
    for (int j = 0; j < 8; ++j) t[j] = base[j * NN];
    return packbf8(t);
}

// A-frag: row-major source, contiguous 32-col window starting at cw
__device__ __forceinline__ bf16x8 afrag_bf16(const __hip_bfloat16* row, int cw, int q) {
    return *(const bf16x8*)((const short*)row + cw + q * 8);
}
__device__ __forceinline__ bf16x8 afrag_f32(const float* row, int cw, int q) {
    float t[8];
    *(float4*)(t)     = *(const float4*)(row + cw + q * 8);
    *(float4*)(t + 4) = *(const float4*)(row + cw + q * 8 + 4);
    return packbf8(t);
}

// ---------------------------------------------------------------------------
// Build per-dst adjacency lists (padded, CAP slots) + per-sign degree counts.
// ---------------------------------------------------------------------------
__global__ __launch_bounds__(256) void pg_build(
    const int* __restrict__ ei,
    int* __restrict__ plist, int* __restrict__ nlist,
    int* __restrict__ pcur, int* __restrict__ ncur, int E)
{
    int e = blockIdx.x * 256 + threadIdx.x;
    if (e >= E) return;
    int s  = ei[3 * e + 0];
    int d  = ei[3 * e + 1];
    int sg = ei[3 * e + 2];
    if (sg > 0) {
        int slot = atomicAdd(pcur + d, 1);
        if (slot < CAP) plist[d * CAP + slot] = s;
    } else {
        int slot = atomicAdd(ncur + d, 1);
        if (slot < CAP) nlist[d * CAP + slot] = s;
    }
}

// ---------------------------------------------------------------------------
// Gather: per node, pos-mean and neg-mean of src rows -> packed bf16 row
//   agg[i] = [ pmean(64) | nmean(64) ]
// ---------------------------------------------------------------------------
__global__ __launch_bounds__(256, 6) void pg_gather(
    const float* __restrict__ src,
    const int* __restrict__ plist, const int* __restrict__ nlist,
    const int* __restrict__ pcur, const int* __restrict__ ncur,
    __hip_bfloat16* __restrict__ agg, int N)
{
    int tid = threadIdx.x;
    int w = tid >> 6, lane = tid & 63;

    #pragma unroll 1
    for (int g = 0; g < 4; ++g) {
        int i0 = blockIdx.x * 64 + w * 16 + g * 4;
        int pd[4], nd[4], pde[4], nde[4], pl[4], nl[4];
        #pragma unroll
        for (int n = 0; n < 4; ++n) {
            int i = min(i0 + n, N - 1);
            pd[n] = __builtin_amdgcn_readfirstlane(pcur[i]);
            nd[n] = __builtin_amdgcn_readfirstlane(ncur[i]);
            pde[n] = min(pd[n], CAP);
            nde[n] = min(nd[n], CAP);
            const int* plrow = plist + (size_t)i * CAP;
            const int* nlrow = nlist + (size_t)i * CAP;
            pl[n] = plrow[lane & 31];
            nl[n] = nlrow[lane & 31];
        }
        int maxd = 0;
        #pragma unroll
        for (int n = 0; n < 4; ++n) maxd = max(maxd, max(pde[n], nde[n]));

        float ps[4] = {0.f, 0.f, 0.f, 0.f}, ns[4] = {0.f, 0.f, 0.f, 0.f};
        #pragma unroll 1
        for (int e = 0; e < maxd; e += 4) {
            float pv[4][4], nv[4][4];
            #pragma unroll
            for (int n = 0; n < 4; ++n) {
                #pragma unroll
                for (int k = 0; k < 4; ++k) {
                    int idx = e + k;
                    int psl = (idx < pde[n]) ? idx : 0;
                    int nsl = (idx < nde[n]) ? idx : 0;
                    unsigned sp = (unsigned)__builtin_amdgcn_readlane(pl[n], psl);
                    unsigned sn = (unsigned)__builtin_amdgcn_readlane(nl[n], nsl);
                    sp = sp < (unsigned)N ? sp : 0u;
                    sn = sn < (unsigned)N ? sn : 0u;
                    const float* prow = src + ((size_t)sp << 6);
                    const float* nrow = src + ((size_t)sn << 6);
                    pv[n][k] = prow[lane];
                    nv[n][k] = nrow[lane];
                }
            }
            #pragma unroll
            for (int n = 0; n < 4; ++n) {
                #pragma unroll
                for (int k = 0; k < 4; ++k) {
                    int idx = e + k;
                    float wp  = (idx < pde[n]) ? 1.f : 0.f;
                    float wn_ = (idx < nde[n]) ? 1.f : 0.f;
                    ps[n] = fmaf(wp,  pv[n][k], ps[n]);
                    ns[n] = fmaf(wn_, nv[n][k], ns[n]);
                }
            }
        }
        #pragma unroll
        for (int n = 0; n < 4; ++n) {
            int i = i0 + n;
            if (i < N) {
                __hip_bfloat16* arow = agg + ((size_t)i << 7);
                arow[lane]      = __float2bfloat16(ps[n] / fmaxf((float)pd[n], 1.f));
                arow[64 + lane] = __float2bfloat16(ns[n] / fmaxf((float)nd[n], 1.f));
            }
        }
    }
}

// ---------------------------------------------------------------------------
// GEMM1 (MFMA): z1 = tanh([ap,x]@Wp1 | [an,x]@Wn1). 16 nodes per wave-tile.
// ---------------------------------------------------------------------------
__global__ __launch_bounds__(256, 3) void pg_gemm1(
    const float* __restrict__ x, const __hip_bfloat16* __restrict__ agg,
    const float* __restrict__ Wp, const float* __restrict__ bp,
    const float* __restrict__ Wn, const float* __restrict__ bn,
    float* __restrict__ z1, int N, int nwv)
{
    int tid = threadIdx.x;
    int w = tid >> 6, lane = tid & 63;
    int q = lane >> 4, c = lane & 15;

    bf16x8 B[2][4][2];
    #pragma unroll
    for (int kt = 0; kt < 4; ++kt)
        #pragma unroll
        for (int ct = 0; ct < 2; ++ct) {
            B[0][kt][ct] = wfrag(Wp, 32, kt, ct, q, c);
            B[1][kt][ct] = wfrag(Wn, 32, kt, ct, q, c);
        }
    float bias[2][2];
    #pragma unroll
    for (int ct = 0; ct < 2; ++ct) {
        bias[0][ct] = bp[ct * 16 + c];
        bias[1][ct] = bn[ct * 16 + c];
    }

    int ntiles = (N + 15) >> 4;
    #pragma unroll 1
    for (int t = blockIdx.x * 4 + w; t < ntiles; t += nwv) {
        int i = min(t * 16 + c, N - 1);
        const __hip_bfloat16* arow = agg + ((size_t)i << 7);
        const float* xrow = x + ((size_t)i << 6);
        bf16x8 aA0 = afrag_bf16(arow, 0, q);
        bf16x8 aA1 = afrag_bf16(arow, 32, q);
        bf16x8 aA2 = afrag_bf16(arow, 64, q);
        bf16x8 aA3 = afrag_bf16(arow, 96, q);
        bf16x8 aX0 = afrag_f32(xrow, 0, q);
        bf16x8 aX1 = afrag_f32(xrow, 32, q);
        f32x4 acc[2][2];
        #pragma unroll
        for (int ct = 0; ct < 2; ++ct) {
            f32x4 a = {0.f, 0.f, 0.f, 0.f};
            a = MFMA(aA0, B[0][0][ct], a);
            a = MFMA(aA1, B[0][1][ct], a);
            a = MFMA(aX0, B[0][2][ct], a);
            a = MFMA(aX1, B[0][3][ct], a);
            acc[0][ct] = a;
            f32x4 b = {0.f, 0.f, 0.f, 0.f};
            b = MFMA(aA2, B[1][0][ct], b);
            b = MFMA(aA3, B[1][1][ct], b);
            b = MFMA(aX0, B[1][2][ct], b);
            b = MFMA(aX1, B[1][3][ct], b);
            acc[1][ct] = b;
        }
        #pragma unroll
        for (int h = 0; h < 2; ++h)
            #pragma unroll
            for (int ct = 0; ct < 2; ++ct)
                #pragma unroll
                for (int r = 0; r < 4; ++r) {
                    int row = t * 16 + q * 4 + r;
                    if (row < N)
                        z1[(size_t)row * 64 + h * 32 + ct * 16 + c] =
                            tanhf(acc[h][ct][r] + bias[h][ct]);
                }
    }
}

// ---------------------------------------------------------------------------
// GEMM2 (MFMA): z2 = tanh([agg-windows, z1]@Wp2 | ...@Wn2); in-place on zio.
// A_p k-windows: agg[0:32], agg[96:128], z1[0:32]
// A_n k-windows: agg[32:64], agg[64:96], z1[32:64]
// ---------------------------------------------------------------------------
__global__ __launch_bounds__(256, 3) void pg_gemm2(
    float* zio, const __hip_bfloat16* __restrict__ agg,
    const float* __restrict__ Wp2, const float* __restrict__ bp2,
    const float* __restrict__ Wn2, const float* __restrict__ bn2,
    int N, int nwv)
{
    int tid = threadIdx.x;
    int w = tid >> 6, lane = tid & 63;
    int q = lane >> 4, c = lane & 15;

    bf16x8 B[2][3][2];
    #pragma unroll
    for (int kt = 0; kt < 3; ++kt)
        #pragma unroll
        for (int ct = 0; ct < 2; ++ct) {
            B[0][kt][ct] = wfrag(Wp2, 32, kt, ct, q, c);
            B[1][kt][ct] = wfrag(Wn2, 32, kt, ct, q, c);
        }
    float bias[2][2];
    #pragma unroll
    for (int ct = 0; ct < 2; ++ct) {
        bias[0][ct] = bp2[ct * 16 + c];
        bias[1][ct] = bn2[ct * 16 + c];
    }

    int ntiles = (N + 15) >> 4;
    #pragma unroll 1
    for (int t = blockIdx.x * 4 + w; t < ntiles; t += nwv) {
        int i = min(t * 16 + c, N - 1);
        const __hip_bfloat16* arow = agg + ((size_t)i << 7);
        const float* zrow = zio + ((size_t)i << 6);
        bf16x8 ap0 = afrag_bf16(arow, 0, q);
        bf16x8 ap1 = afrag_bf16(arow, 96, q);
        bf16x8 an0 = afrag_bf16(arow, 32, q);
        bf16x8 an1 = afrag_bf16(arow, 64, q);
        bf16x8 az0 = afrag_f32(zrow, 0, q);
        bf16x8 az1 = afrag_f32(zrow, 32, q);
        f32x4 acc[2][2];
        #pragma unroll
        for (int ct = 0; ct < 2; ++ct) {
            f32x4 a = {0.f, 0.f, 0.f, 0.f};
            a = MFMA(ap0, B[0][0][ct], a);
            a = MFMA(ap1, B[0][1][ct], a);
            a = MFMA(az0, B[0][2][ct], a);
            acc[0][ct] = a;
            f32x4 b = {0.f, 0.f, 0.f, 0.f};
            b = MFMA(an0, B[1][0][ct], b);
            b = MFMA(an1, B[1][1][ct], b);
            b = MFMA(az1, B[1][2][ct], b);
            acc[1][ct] = b;
        }
        #pragma unroll
        for (int h = 0; h < 2; ++h)
            #pragma unroll
            for (int ct = 0; ct < 2; ++ct)
                #pragma unroll
                for (int r = 0; r < 4; ++r) {
                    int row = t * 16 + q * 4 + r;
                    if (row < N)
                        zio[(size_t)row * 64 + h * 32 + ct * 16 + c] =
                            tanhf(acc[h][ct][r] + bias[h][ct]);
                }
    }
}

// ---------------------------------------------------------------------------
// MLP head (MFMA chain): z = tanh(z2@Ww+bw) -> out; BN/ReLU x2; dot Wm3 ->
// sigmoid prob. Wave-private LDS transpose [16][68] between stages.
// ---------------------------------------------------------------------------
__global__ __launch_bounds__(256, 2) void pg_mlp(
    float* out,
    const float* __restrict__ Ww,  const float* __restrict__ bw,
    const float* __restrict__ Wm1, const float* __restrict__ bm1,
    const float* __restrict__ g1,  const float* __restrict__ be1,
    const float* __restrict__ rm1, const float* __restrict__ rv1,
    const float* __restrict__ Wm2, const float* __restrict__ bm2,
    const float* __restrict__ g2,  const float* __restrict__ be2,
    const float* __restrict__ rm2, const float* __restrict__ rv2,
    const float* __restrict__ Wm3, const float* __restrict__ bm3,
    int N, int nwv)
{
    __shared__ float xpos[4][16][68];
    int tid = threadIdx.x;
    int w = tid >> 6, lane = tid & 63;
    int q = lane >> 4, c = lane & 15;
    float (*lx)[68] = xpos[w];

    bf16x8 Bw[2][4], B1[2][4], B2[2][4];
    #pragma unroll
    for (int kt = 0; kt < 2; ++kt)
        #pragma unroll
        for (int ct = 0; ct < 4; ++ct) {
            Bw[kt][ct] = wfrag(Ww,  64, kt, ct, q, c);
            B1[kt][ct] = wfrag(Wm1, 64, kt, ct, q, c);
            B2[kt][ct] = wfrag(Wm2, 64, kt, ct, q, c);
        }
    float bwv[4], s1[4], o1[4], s2[4], o2[4], w3[4];
    #pragma unroll
    for (int ct = 0; ct < 4; ++ct) {
        int cc = ct * 16 + c;
        bwv[ct] = bw[cc];
        float a = g1[cc] * rsqrtf(rv1[cc] + 1e-5f);
        s1[ct] = a; o1[ct] = (bm1[cc] - rm1[cc]) * a + be1[cc];
        float b = g2[cc] * rsqrtf(rv2[cc] + 1e-5f);
        s2[ct] = b; o2[ct] = (bm2[cc] - rm2[cc]) * b + be2[cc];
        w3[ct] = Wm3[cc];
    }
    float b3 = bm3[0];

    int ntiles = (N + 15) >> 4;
    #pragma unroll 1
    for (int t = blockIdx.x * 4 + w; t < ntiles; t += nwv) {
        int i = min(t * 16 + c, N - 1);
        const float* zrow = out + ((size_t)i << 6);
        bf16x8 a0 = afrag_f32(zrow, 0, q);
        bf16x8 a1 = afrag_f32(zrow, 32, q);
        f32x4 acc[4];

        // ---- Ww -> tanh -> final z (global + LDS) ----
        #pragma unroll
        for (int ct = 0; ct < 4; ++ct) {
            f32x4 a = {0.f, 0.f, 0.f, 0.f};
            a = MFMA(a0, Bw[0][ct], a);
            a = MFMA(a1, Bw[1][ct], a);
            acc[ct] = a;
        }
        #pragma unroll
        for (int ct = 0; ct < 4; ++ct)
            #pragma unroll
            for (int r = 0; r < 4; ++r) {
                int row = t * 16 + q * 4 + r;
                float v = tanhf(acc[ct][r] + bwv[ct]);
                if (row < N) out[(size_t)row * 64 + ct * 16 + c] = v;
                lx[q * 4 + r][ct * 16 + c] = v;
            }
        {
            const float* pr = &lx[c][0];
            float tb[8];
            *(float4*)tb       = *(const float4*)(pr + q * 8);
            *(float4*)(tb + 4) = *(const float4*)(pr + q * 8 + 4);
            a0 = packbf8(tb);
            *(float4*)tb       = *(const float4*)(pr + 32 + q * 8);
            *(float4*)(tb + 4) = *(const float4*)(pr + 32 + q * 8 + 4);
            a1 = packbf8(tb);
        }

        // ---- Wm1 -> BN -> ReLU ----
        #pragma unroll
        for (int ct = 0; ct < 4; ++ct) {
            f32x4 a = {0.f, 0.f, 0.f, 0.f};
            a = MFMA(a0, B1[0][ct], a);
            a = MFMA(a1, B1[1][ct], a);
            acc[ct] = a;
        }
        #pragma unroll
        for (int ct = 0; ct < 4; ++ct)
            #pragma unroll
            for (int r = 0; r < 4; ++r)
                lx[q * 4 + r][ct * 16 + c] = fmaxf(acc[ct][r] * s1[ct] + o1[ct], 0.f);
        {
            const float* pr = &lx[c][0];
            float tb[8];
            *(float4*)tb       = *(const float4*)(pr + q * 8);
            *(float4*)(tb + 4) = *(const float4*)(pr + q * 8 + 4);
            a0 = packbf8(tb);
            *(float4*)tb       = *(const float4*)(pr + 32 + q * 8);
            *(float4*)(tb + 4) = *(const float4*)(pr + 32 + q * 8 + 4);
            a1 = packbf8(tb);
        }

        // ---- Wm2 -> BN -> ReLU -> dot Wm3 -> sigmoid ----
        #pragma unroll
        for (int ct = 0; ct < 4; ++ct) {
            f32x4 a = {0.f, 0.f, 0.f, 0.f};
            a = MFMA(a0, B2[0][ct], a);
            a = MFMA(a1, B2[1][ct], a);
            acc[ct] = a;
        }
        float tr[4];
        #pragma unroll
        for (int r = 0; r < 4; ++r) {
            float hs = 0.f;
            #pragma unroll
            for (int ct = 0; ct < 4; ++ct) {
                float h2 = fmaxf(acc[ct][r] * s2[ct] + o2[ct], 0.f);
                hs = fmaf(h2, w3[ct], hs);
            }
            tr[r] = hs;
        }
        #pragma unroll
        for (int m = 1; m < 16; m <<= 1)
            #pragma unroll
            for (int r = 0; r < 4; ++r) tr[r] += __shfl_xor(tr[r], m, 16);
        if (c == 0) {
            #pragma unroll
            for (int r = 0; r < 4; ++r) {
                int row = t * 16 + q * 4 + r;
                if (row < N)
                    out[(size_t)N * 64 + row] = 1.f / (1.f + expf(-(tr[r] + b3)));
            }
        }
    }
}

extern "C" void kernel_launch(void* const* d_in, const int* in_sizes, int n_in,
                              void* d_out, int out_size, void* d_ws, size_t ws_size,
                              hipStream_t stream) {
    const float* x   = (const float*)d_in[0];
    const int*   ei  = (const int*)  d_in[1];
    const float* Wp1 = (const float*)d_in[2];
    const float* bp1 = (const float*)d_in[3];
    const float* Wn1 = (const float*)d_in[4];
    const float* bn1 = (const float*)d_in[5];
    const float* Wp2 = (const float*)d_in[6];
    const float* bp2 = (const float*)d_in[7];
    const float* Wn2 = (const float*)d_in[8];
    const float* bn2 = (const float*)d_in[9];
    const float* Ww  = (const float*)d_in[10];
    const float* bw  = (const float*)d_in[11];
    const float* Wm1 = (const float*)d_in[12];
    const float* bm1 = (const float*)d_in[13];
    const float* g1  = (const float*)d_in[14];
    const float* be1 = (const float*)d_in[15];
    const float* rm1 = (const float*)d_in[16];
    const float* rv1 = (const float*)d_in[17];
    const float* Wm2 = (const float*)d_in[18];
    const float* bm2 = (const float*)d_in[19];
    const float* g2  = (const float*)d_in[20];
    const float* be2 = (const float*)d_in[21];
    const float* rm2 = (const float*)d_in[22];
    const float* rv2 = (const float*)d_in[23];
    const float* Wm3 = (const float*)d_in[24];
    const float* bm3 = (const float*)d_in[25];
    float* out = (float*)d_out;

    int N = in_sizes[0] / 64;
    int E = in_sizes[1] / 3;

    // ws layout (52.0 MB for N=100K): plist | nlist | pcur | ncur | agg(bf16 N x 128)
    int* plist = (int*)d_ws;
    int* nlist = plist + (size_t)N * CAP;
    int* pcur  = nlist + (size_t)N * CAP;
    int* ncur  = pcur + N;
    __hip_bfloat16* agg = (__hip_bfloat16*)(ncur + N);
    float* zio = out;   // z1/z2/z staged in d_out's z region (row-local rewrites)

    hipMemsetAsync(pcur, 0, 2 * (size_t)N * sizeof(int), stream);

    pg_build<<<(E + 255) / 256, 256, 0, stream>>>(ei, plist, nlist, pcur, ncur, E);

    int nb = (N + 63) / 64;
    const int gb = 512, nwv = gb * 4;
    pg_gather<<<nb, 256, 0, stream>>>(x, plist, nlist, pcur, ncur, agg, N);
    pg_gemm1<<<gb, 256, 0, stream>>>(x, agg, Wp1, bp1, Wn1, bn1, zio, N, nwv);
    pg_gather<<<nb, 256, 0, stream>>>(zio, plist, nlist, pcur, ncur, agg, N);
    pg_gemm2<<<gb, 256, 0, stream>>>(zio, agg, Wp2, bp2, Wn2, bn2, N, nwv);
    pg_mlp<<<gb, 256, 0, stream>>>(out, Ww, bw,
                                   Wm1, bm1, g1, be1, rm1, rv1,
                                   Wm2, bm2, g2, be2, rm2, rv2,
                                   Wm3, bm3, N, nwv);
}

// Round 8
// 257.378 us; speedup vs baseline: 1.5541x; 1.0660x over previous
//
#include <hip/hip_runtime.h>
#include <hip/hip_bf16.h>

#define CAP 32   // padded adjacency slots per node per sign (Poisson λ≈6.25)

typedef __attribute__((ext_vector_type(8))) short bf16x8;
typedef __attribute__((ext_vector_type(4))) float f32x4;

#define MFMA(a, b, c) __builtin_amdgcn_mfma_f32_16x16x32_bf16(a, b, c, 0, 0, 0)

__device__ __forceinline__ unsigned short bf16rn(float f) {
    unsigned u = __builtin_bit_cast(unsigned, f);
    u += 0x7fffu + ((u >> 16) & 1u);
    return (unsigned short)(u >> 16);
}

__device__ __forceinline__ bf16x8 packbf8(const float* p) {
    bf16x8 r;
    #pragma unroll
    for (int j = 0; j < 8; ++j) r[j] = (short)bf16rn(p[j]);
    return r;
}

// B-frag from row-major f32 W[K][NN]: elem j = W[kt*32 + q*8 + j][ct*16 + c]
__device__ __forceinline__ bf16x8 wfrag(const float* __restrict__ W, int NN,
                                        int kt, int ct, int q, int c) {
    const float* base = W + (kt * 32 + q * 8) * NN + ct * 16 + c;
    float t[8];
    #pragma unroll
    for (int j = 0; j < 8; ++j) t[j] = base[j * NN];
    return packbf8(t);
}

// A-frag: row-major bf16 source, contiguous 32-col window starting at cw
__device__ __forceinline__ bf16x8 afrag_bf16(const __hip_bfloat16* row, int cw, int q) {
    return *(const bf16x8*)((const short*)row + cw + q * 8);
}

// ---------------------------------------------------------------------------
// Cast x (f32) -> xb (bf16), vectorized.
// ---------------------------------------------------------------------------
__global__ __launch_bounds__(256) void pg_cast(
    const float* __restrict__ x, __hip_bfloat16* __restrict__ xb, int n)
{
    int i = (blockIdx.x * 256 + threadIdx.x) * 4;
    if (i < n) {
        float4 v = *(const float4*)(x + i);
        ushort4 o;
        o.x = bf16rn(v.x); o.y = bf16rn(v.y);
        o.z = bf16rn(v.z); o.w = bf16rn(v.w);
        *(ushort4*)((unsigned short*)xb + i) = o;
    }
}

// ---------------------------------------------------------------------------
// Build per-dst adjacency lists (padded, CAP slots) + per-sign degree counts.
// Branchless sign select -> single atomic per edge.
// ---------------------------------------------------------------------------
__global__ __launch_bounds__(256) void pg_build(
    const int* __restrict__ ei,
    int* __restrict__ plist, int* __restrict__ nlist,
    int* __restrict__ pcur, int* __restrict__ ncur, int E)
{
    int e = blockIdx.x * 256 + threadIdx.x;
    if (e >= E) return;
    int s  = ei[3 * e + 0];
    int d  = ei[3 * e + 1];
    int sg = ei[3 * e + 2];
    int* cur  = (sg > 0) ? pcur : ncur;
    int* list = (sg > 0) ? plist : nlist;
    int slot = atomicAdd(cur + d, 1);
    if (slot < CAP) list[(size_t)d * CAP + slot] = s;
}

// ---------------------------------------------------------------------------
// Gather: per node, pos-mean and neg-mean of bf16 src rows -> packed bf16 row
//   agg[i] = [ pmean(64) | nmean(64) ]
// ---------------------------------------------------------------------------
__global__ __launch_bounds__(256, 6) void pg_gather(
    const __hip_bfloat16* __restrict__ src,
    const int* __restrict__ plist, const int* __restrict__ nlist,
    const int* __restrict__ pcur, const int* __restrict__ ncur,
    __hip_bfloat16* __restrict__ agg, int N)
{
    int tid = threadIdx.x;
    int w = tid >> 6, lane = tid & 63;

    #pragma unroll 1
    for (int g = 0; g < 4; ++g) {
        int i0 = blockIdx.x * 64 + w * 16 + g * 4;
        int pd[4], nd[4], pde[4], nde[4], pl[4], nl[4];
        #pragma unroll
        for (int n = 0; n < 4; ++n) {
            int i = min(i0 + n, N - 1);
            pd[n] = __builtin_amdgcn_readfirstlane(pcur[i]);
            nd[n] = __builtin_amdgcn_readfirstlane(ncur[i]);
            pde[n] = min(pd[n], CAP);
            nde[n] = min(nd[n], CAP);
            const int* plrow = plist + (size_t)i * CAP;
            const int* nlrow = nlist + (size_t)i * CAP;
            pl[n] = plrow[lane & 31];
            nl[n] = nlrow[lane & 31];
        }
        int maxd = 0;
        #pragma unroll
        for (int n = 0; n < 4; ++n) maxd = max(maxd, max(pde[n], nde[n]));

        float ps[4] = {0.f, 0.f, 0.f, 0.f}, ns[4] = {0.f, 0.f, 0.f, 0.f};
        #pragma unroll 1
        for (int e = 0; e < maxd; e += 4) {
            float pv[4][4], nv[4][4];
            #pragma unroll
            for (int n = 0; n < 4; ++n) {
                #pragma unroll
                for (int k = 0; k < 4; ++k) {
                    int idx = e + k;
                    int psl = (idx < pde[n]) ? idx : 0;
                    int nsl = (idx < nde[n]) ? idx : 0;
                    unsigned sp = (unsigned)__builtin_amdgcn_readlane(pl[n], psl);
                    unsigned sn = (unsigned)__builtin_amdgcn_readlane(nl[n], nsl);
                    sp = sp < (unsigned)N ? sp : 0u;
                    sn = sn < (unsigned)N ? sn : 0u;
                    const __hip_bfloat16* prow = src + ((size_t)sp << 6);
                    const __hip_bfloat16* nrow = src + ((size_t)sn << 6);
                    pv[n][k] = __bfloat162float(prow[lane]);
                    nv[n][k] = __bfloat162float(nrow[lane]);
                }
            }
            #pragma unroll
            for (int n = 0; n < 4; ++n) {
                #pragma unroll
                for (int k = 0; k < 4; ++k) {
                    int idx = e + k;
                    float wp  = (idx < pde[n]) ? 1.f : 0.f;
                    float wn_ = (idx < nde[n]) ? 1.f : 0.f;
                    ps[n] = fmaf(wp,  pv[n][k], ps[n]);
                    ns[n] = fmaf(wn_, nv[n][k], ns[n]);
                }
            }
        }
        #pragma unroll
        for (int n = 0; n < 4; ++n) {
            int i = i0 + n;
            if (i < N) {
                __hip_bfloat16* arow = agg + ((size_t)i << 7);
                arow[lane]      = __float2bfloat16(ps[n] / fmaxf((float)pd[n], 1.f));
                arow[64 + lane] = __float2bfloat16(ns[n] / fmaxf((float)nd[n], 1.f));
            }
        }
    }
}

// ---------------------------------------------------------------------------
// GEMM1 (MFMA): z1b = tanh([ap,x]@Wp1 | [an,x]@Wn1), bf16 in / bf16 out.
// ---------------------------------------------------------------------------
__global__ __launch_bounds__(256, 3) void pg_gemm1(
    const __hip_bfloat16* __restrict__ xb, const __hip_bfloat16* __restrict__ agg,
    const float* __restrict__ Wp, const float* __restrict__ bp,
    const float* __restrict__ Wn, const float* __restrict__ bn,
    __hip_bfloat16* __restrict__ z1b, int N, int nwv)
{
    int tid = threadIdx.x;
    int w = tid >> 6, lane = tid & 63;
    int q = lane >> 4, c = lane & 15;

    bf16x8 B[2][4][2];
    #pragma unroll
    for (int kt = 0; kt < 4; ++kt)
        #pragma unroll
        for (int ct = 0; ct < 2; ++ct) {
            B[0][kt][ct] = wfrag(Wp, 32, kt, ct, q, c);
            B[1][kt][ct] = wfrag(Wn, 32, kt, ct, q, c);
        }
    float bias[2][2];
    #pragma unroll
    for (int ct = 0; ct < 2; ++ct) {
        bias[0][ct] = bp[ct * 16 + c];
        bias[1][ct] = bn[ct * 16 + c];
    }

    int ntiles = (N + 15) >> 4;
    #pragma unroll 1
    for (int t = blockIdx.x * 4 + w; t < ntiles; t += nwv) {
        int i = min(t * 16 + c, N - 1);
        const __hip_bfloat16* arow = agg + ((size_t)i << 7);
        const __hip_bfloat16* xrow = xb + ((size_t)i << 6);
        bf16x8 aA0 = afrag_bf16(arow, 0, q);
        bf16x8 aA1 = afrag_bf16(arow, 32, q);
        bf16x8 aA2 = afrag_bf16(arow, 64, q);
        bf16x8 aA3 = afrag_bf16(arow, 96, q);
        bf16x8 aX0 = afrag_bf16(xrow, 0, q);
        bf16x8 aX1 = afrag_bf16(xrow, 32, q);
        f32x4 acc[2][2];
        #pragma unroll
        for (int ct = 0; ct < 2; ++ct) {
            f32x4 a = {0.f, 0.f, 0.f, 0.f};
            a = MFMA(aA0, B[0][0][ct], a);
            a = MFMA(aA1, B[0][1][ct], a);
            a = MFMA(aX0, B[0][2][ct], a);
            a = MFMA(aX1, B[0][3][ct], a);
            acc[0][ct] = a;
            f32x4 b = {0.f, 0.f, 0.f, 0.f};
            b = MFMA(aA2, B[1][0][ct], b);
            b = MFMA(aA3, B[1][1][ct], b);
            b = MFMA(aX0, B[1][2][ct], b);
            b = MFMA(aX1, B[1][3][ct], b);
            acc[1][ct] = b;
        }
        #pragma unroll
        for (int h = 0; h < 2; ++h)
            #pragma unroll
            for (int ct = 0; ct < 2; ++ct)
                #pragma unroll
                for (int r = 0; r < 4; ++r) {
                    int row = t * 16 + q * 4 + r;
                    if (row < N)
                        z1b[(size_t)row * 64 + h * 32 + ct * 16 + c] =
                            __float2bfloat16(tanhf(acc[h][ct][r] + bias[h][ct]));
                }
    }
}

// ---------------------------------------------------------------------------
// GEMM2 (MFMA): z2 = tanh([agg-windows, z1]@Wp2 | ...@Wn2).
// z2b written bf16 into agg region cols 0..63 (stride 128) -> row-local, safe.
// ---------------------------------------------------------------------------
__global__ __launch_bounds__(256, 3) void pg_gemm2(
    const __hip_bfloat16* __restrict__ z1b, __hip_bfloat16* agg,
    const float* __restrict__ Wp2, const float* __restrict__ bp2,
    const float* __restrict__ Wn2, const float* __restrict__ bn2,
    int N, int nwv)
{
    int tid = threadIdx.x;
    int w = tid >> 6, lane = tid & 63;
    int q = lane >> 4, c = lane & 15;

    bf16x8 B[2][3][2];
    #pragma unroll
    for (int kt = 0; kt < 3; ++kt)
        #pragma unroll
        for (int ct = 0; ct < 2; ++ct) {
            B[0][kt][ct] = wfrag(Wp2, 32, kt, ct, q, c);
            B[1][kt][ct] = wfrag(Wn2, 32, kt, ct, q, c);
        }
    float bias[2][2];
    #pragma unroll
    for (int ct = 0; ct < 2; ++ct) {
        bias[0][ct] = bp2[ct * 16 + c];
        bias[1][ct] = bn2[ct * 16 + c];
    }

    int ntiles = (N + 15) >> 4;
    #pragma unroll 1
    for (int t = blockIdx.x * 4 + w; t < ntiles; t += nwv) {
        int i = min(t * 16 + c, N - 1);
        const __hip_bfloat16* arow = agg + ((size_t)i << 7);
        const __hip_bfloat16* zrow = z1b + ((size_t)i << 6);
        bf16x8 ap0 = afrag_bf16(arow, 0, q);
        bf16x8 ap1 = afrag_bf16(arow, 96, q);
        bf16x8 an0 = afrag_bf16(arow, 32, q);
        bf16x8 an1 = afrag_bf16(arow, 64, q);
        bf16x8 az0 = afrag_bf16(zrow, 0, q);
        bf16x8 az1 = afrag_bf16(zrow, 32, q);
        f32x4 acc[2][2];
        #pragma unroll
        for (int ct = 0; ct < 2; ++ct) {
            f32x4 a = {0.f, 0.f, 0.f, 0.f};
            a = MFMA(ap0, B[0][0][ct], a);
            a = MFMA(ap1, B[0][1][ct], a);
            a = MFMA(az0, B[0][2][ct], a);
            acc[0][ct] = a;
            f32x4 b = {0.f, 0.f, 0.f, 0.f};
            b = MFMA(an0, B[1][0][ct], b);
            b = MFMA(an1, B[1][1][ct], b);
            b = MFMA(az1, B[1][2][ct], b);
            acc[1][ct] = b;
        }
        #pragma unroll
        for (int h = 0; h < 2; ++h)
            #pragma unroll
            for (int ct = 0; ct < 2; ++ct)
                #pragma unroll
                for (int r = 0; r < 4; ++r) {
                    int row = t * 16 + q * 4 + r;
                    if (row < N)
                        agg[(size_t)row * 128 + h * 32 + ct * 16 + c] =
                            __float2bfloat16(tanhf(acc[h][ct][r] + bias[h][ct]));
                }
    }
}

// ---------------------------------------------------------------------------
// MLP head (MFMA chain): z = tanh(z2@Ww+bw) -> out; BN/ReLU x2; dot Wm3 ->
// sigmoid prob. z2b read bf16 (stride 128). LDS transpose between stages.
// ---------------------------------------------------------------------------
__global__ __launch_bounds__(256, 2) void pg_mlp(
    float* out, const __hip_bfloat16* __restrict__ z2b,
    const float* __restrict__ Ww,  const float* __restrict__ bw,
    const float* __restrict__ Wm1, const float* __restrict__ bm1,
    const float* __restrict__ g1,  const float* __restrict__ be1,
    const float* __restrict__ rm1, const float* __restrict__ rv1,
    const float* __restrict__ Wm2, const float* __restrict__ bm2,
    const float* __restrict__ g2,  const float* __restrict__ be2,
    const float* __restrict__ rm2, const float* __restrict__ rv2,
    const float* __restrict__ Wm3, const float* __restrict__ bm3,
    int N, int nwv)
{
    __shared__ float xpos[4][16][68];
    int tid = threadIdx.x;
    int w = tid >> 6, lane = tid & 63;
    int q = lane >> 4, c = lane & 15;
    float (*lx)[68] = xpos[w];

    bf16x8 Bw[2][4], B1[2][4], B2[2][4];
    #pragma unroll
    for (int kt = 0; kt < 2; ++kt)
        #pragma unroll
        for (int ct = 0; ct < 4; ++ct) {
            Bw[kt][ct] = wfrag(Ww,  64, kt, ct, q, c);
            B1[kt][ct] = wfrag(Wm1, 64, kt, ct, q, c);
            B2[kt][ct] = wfrag(Wm2, 64, kt, ct, q, c);
        }
    float bwv[4], s1[4], o1[4], s2[4], o2[4], w3[4];
    #pragma unroll
    for (int ct = 0; ct < 4; ++ct) {
        int cc = ct * 16 + c;
        bwv[ct] = bw[cc];
        float a = g1[cc] * rsqrtf(rv1[cc] + 1e-5f);
        s1[ct] = a; o1[ct] = (bm1[cc] - rm1[cc]) * a + be1[cc];
        float b = g2[cc] * rsqrtf(rv2[cc] + 1e-5f);
        s2[ct] = b; o2[ct] = (bm2[cc] - rm2[cc]) * b + be2[cc];
        w3[ct] = Wm3[cc];
    }
    float b3 = bm3[0];

    int ntiles = (N + 15) >> 4;
    #pragma unroll 1
    for (int t = blockIdx.x * 4 + w; t < ntiles; t += nwv) {
        int i = min(t * 16 + c, N - 1);
        const __hip_bfloat16* zrow = z2b + ((size_t)i << 7);
        bf16x8 a0 = afrag_bf16(zrow, 0, q);
        bf16x8 a1 = afrag_bf16(zrow, 32, q);
        f32x4 acc[4];

        // ---- Ww -> tanh -> final z (global + LDS) ----
        #pragma unroll
        for (int ct = 0; ct < 4; ++ct) {
            f32x4 a = {0.f, 0.f, 0.f, 0.f};
            a = MFMA(a0, Bw[0][ct], a);
            a = MFMA(a1, Bw[1][ct], a);
            acc[ct] = a;
        }
        #pragma unroll
        for (int ct = 0; ct < 4; ++ct)
            #pragma unroll
            for (int r = 0; r < 4; ++r) {
                int row = t * 16 + q * 4 + r;
                float v = tanhf(acc[ct][r] + bwv[ct]);
                if (row < N) out[(size_t)row * 64 + ct * 16 + c] = v;
                lx[q * 4 + r][ct * 16 + c] = v;
            }
        {
            const float* pr = &lx[c][0];
            float tb[8];
            *(float4*)tb       = *(const float4*)(pr + q * 8);
            *(float4*)(tb + 4) = *(const float4*)(pr + q * 8 + 4);
            a0 = packbf8(tb);
            *(float4*)tb       = *(const float4*)(pr + 32 + q * 8);
            *(float4*)(tb + 4) = *(const float4*)(pr + 32 + q * 8 + 4);
            a1 = packbf8(tb);
        }

        // ---- Wm1 -> BN -> ReLU ----
        #pragma unroll
        for (int ct = 0; ct < 4; ++ct) {
            f32x4 a = {0.f, 0.f, 0.f, 0.f};
            a = MFMA(a0, B1[0][ct], a);
            a = MFMA(a1, B1[1][ct], a);
            acc[ct] = a;
        }
        #pragma unroll
        for (int ct = 0; ct < 4; ++ct)
            #pragma unroll
            for (int r = 0; r < 4; ++r)
                lx[q * 4 + r][ct * 16 + c] = fmaxf(acc[ct][r] * s1[ct] + o1[ct], 0.f);
        {
            const float* pr = &lx[c][0];
            float tb[8];
            *(float4*)tb       = *(const float4*)(pr + q * 8);
            *(float4*)(tb + 4) = *(const float4*)(pr + q * 8 + 4);
            a0 = packbf8(tb);
            *(float4*)tb       = *(const float4*)(pr + 32 + q * 8);
            *(float4*)(tb + 4) = *(const float4*)(pr + 32 + q * 8 + 4);
            a1 = packbf8(tb);
        }

        // ---- Wm2 -> BN -> ReLU -> dot Wm3 -> sigmoid ----
        #pragma unroll
        for (int ct = 0; ct < 4; ++ct) {
            f32x4 a = {0.f, 0.f, 0.f, 0.f};
            a = MFMA(a0, B2[0][ct], a);
            a = MFMA(a1, B2[1][ct], a);
            acc[ct] = a;
        }
        float tr[4];
        #pragma unroll
        for (int r = 0; r < 4; ++r) {
            float hs = 0.f;
            #pragma unroll
            for (int ct = 0; ct < 4; ++ct) {
                float h2 = fmaxf(acc[ct][r] * s2[ct] + o2[ct], 0.f);
                hs = fmaf(h2, w3[ct], hs);
            }
            tr[r] = hs;
        }
        #pragma unroll
        for (int m = 1; m < 16; m <<= 1)
            #pragma unroll
            for (int r = 0; r < 4; ++r) tr[r] += __shfl_xor(tr[r], m, 16);
        if (c == 0) {
            #pragma unroll
            for (int r = 0; r < 4; ++r) {
                int row = t * 16 + q * 4 + r;
                if (row < N)
                    out[(size_t)N * 64 + row] = 1.f / (1.f + expf(-(tr[r] + b3)));
            }
        }
    }
}

extern "C" void kernel_launch(void* const* d_in, const int* in_sizes, int n_in,
                              void* d_out, int out_size, void* d_ws, size_t ws_size,
                              hipStream_t stream) {
    const float* x   = (const float*)d_in[0];
    const int*   ei  = (const int*)  d_in[1];
    const float* Wp1 = (const float*)d_in[2];
    const float* bp1 = (const float*)d_in[3];
    const float* Wn1 = (const float*)d_in[4];
    const float* bn1 = (const float*)d_in[5];
    const float* Wp2 = (const float*)d_in[6];
    const float* bp2 = (const float*)d_in[7];
    const float* Wn2 = (const float*)d_in[8];
    const float* bn2 = (const float*)d_in[9];
    const float* Ww  = (const float*)d_in[10];
    const float* bw  = (const float*)d_in[11];
    const float* Wm1 = (const float*)d_in[12];
    const float* bm1 = (const float*)d_in[13];
    const float* g1  = (const float*)d_in[14];
    const float* be1 = (const float*)d_in[15];
    const float* rm1 = (const float*)d_in[16];
    const float* rv1 = (const float*)d_in[17];
    const float* Wm2 = (const float*)d_in[18];
    const float* bm2 = (const float*)d_in[19];
    const float* g2  = (const float*)d_in[20];
    const float* be2 = (const float*)d_in[21];
    const float* rm2 = (const float*)d_in[22];
    const float* rv2 = (const float*)d_in[23];
    const float* Wm3 = (const float*)d_in[24];
    const float* bm3 = (const float*)d_in[25];
    float* out = (float*)d_out;

    int N = in_sizes[0] / 64;
    int E = in_sizes[1] / 3;

    // ws layout (52.0 MB for N=100K): plist | nlist | pcur | ncur | agg(bf16 N x 128)
    int* plist = (int*)d_ws;
    int* nlist = plist + (size_t)N * CAP;
    int* pcur  = nlist + (size_t)N * CAP;
    int* ncur  = pcur + N;
    __hip_bfloat16* agg = (__hip_bfloat16*)(ncur + N);   // also hosts z2b (stride 128)

    // d_out z region (N*256 bytes) staging: z1b = first half, xb = second half.
    // Both are dead by the time pg_mlp overwrites the region with final z.
    __hip_bfloat16* z1b = (__hip_bfloat16*)out;                          // N x 64
    __hip_bfloat16* xb  = (__hip_bfloat16*)((char*)d_out + (size_t)N * 128); // N x 64

    pg_cast<<<(N * 64 / 4 + 255) / 256, 256, 0, stream>>>(x, xb, N * 64);

    hipMemsetAsync(pcur, 0, 2 * (size_t)N * sizeof(int), stream);
    pg_build<<<(E + 255) / 256, 256, 0, stream>>>(ei, plist, nlist, pcur, ncur, E);

    int nb = (N + 63) / 64;
    const int gb = 512, nwv = gb * 4;
    pg_gather<<<nb, 256, 0, stream>>>(xb, plist, nlist, pcur, ncur, agg, N);
    pg_gemm1<<<gb, 256, 0, stream>>>(xb, agg, Wp1, bp1, Wn1, bn1, z1b, N, nwv);
    pg_gather<<<nb, 256, 0, stream>>>(z1b, plist, nlist, pcur, ncur, agg, N);
    pg_gemm2<<<gb, 256, 0, stream>>>(z1b, agg, Wp2, bp2, Wn2, bn2, N, nwv);
    pg_mlp<<<gb, 256, 0, stream>>>(out, agg, Ww, bw,
                                   Wm1, bm1, g1, be1, rm1, rv1,
                                   Wm2, bm2, g2, be2, rm2, rv2,
                                   Wm3, bm3, N, nwv);
}